// Round 12
// baseline (88.414 us; speedup 1.0000x reference)
//
#include <hip/hip_runtime.h>
#include <hip/hip_bf16.h>
#include <stdint.h>

// Shapes (fixed): S=4, B=2, F=64, P=16, T=32, H=64, W=64, HID=32
#define THW   131072   // 32*64*64
#define NS    4
#define NB    2
#define NF    64
#define NP    16
#define HID   32
#define BN_EPS 1e-5f
#define PXT   128      // pixels per block tile (4 waves x 32-px MFMA tiles)

typedef short  bf16x8  __attribute__((ext_vector_type(8)));
typedef float  f32x16  __attribute__((ext_vector_type(16)));

union FragU { uint32_t u[4]; bf16x8 v; uint4 q; };

__device__ __forceinline__ uint32_t pk2(float a, float b) {
    __hip_bfloat162 h = __float22bfloat162_rn(make_float2(a, b));
    uint32_t r;
    __builtin_memcpy(&r, &h, sizeof(r));
    return r;
}
__device__ __forceinline__ float lo16(uint32_t u) { return __builtin_bit_cast(float, u << 16); }
__device__ __forceinline__ float hi16(uint32_t u) { return __builtin_bit_cast(float, u & 0xFFFF0000u); }

// Barrier that does NOT drain vmcnt (keeps prefetch loads in flight).
// __syncthreads() emits s_waitcnt vmcnt(0) — kills the depth-2 pipeline.
__device__ __forceinline__ void lds_barrier() {
    asm volatile("s_waitcnt lgkmcnt(0)" ::: "memory");
    __builtin_amdgcn_s_barrier();
}

// R12 = R10 shape (256thr, PXT=128, 2 blk/CU, brev11) + R11 bf16-LDS
// (direct dword frag reads) + DEPTH-2 reg-staged pipeline:
//   phase s: issue loads(s+2) -> consume(s) -> write(s+1) [vmcnt waits here,
//   ~2 phases after issue] -> lgkmcnt-only barrier.
__global__ __launch_bounds__(256, 2) void gssm_kernel(
    const float* __restrict__ feats, const float* __restrict__ ps,
    const float* __restrict__ w1,    const float* __restrict__ gamma,
    const float* __restrict__ beta,  const float* __restrict__ mean,
    const float* __restrict__ var,   const float* __restrict__ w2,
    float* __restrict__ out)
{
    __shared__ __align__(16) uint32_t fbuf[2][NF / 2][PXT];  // 32768 B (bf16 pairs {2fp,2fp+1})
    __shared__ __align__(16) uint32_t pbuf[NP / 2][PXT];     //  4096 B
    __shared__ __align__(16) uint32_t w1lds[32 * 44];        //  5632 B
    __shared__ float2 tbl[HID];                              //   256 B

    const int tid  = threadIdx.x;
    const int lane = tid & 63;
    const int wv   = tid >> 6;      // 0..3
    const int hi   = lane >> 5;
    const int ln   = lane & 31;

    // ---- stage w1 (BN-scale folded, bf16-packed) + tbl
    for (int t = tid; t < 1280; t += 256) {
        float2 v = ((const float2*)w1)[t];
        int o = t / 40, cp = t - o * 40;
        float sc = gamma[o] * rsqrtf(var[o] + BN_EPS);
        w1lds[o * 44 + (cp >> 3) * 8 + (cp & 7)] = pk2(v.x * sc, v.y * sc);
    }
    if (tid < HID) {
        float sc = gamma[tid] * rsqrtf(var[tid] + BN_EPS);
        tbl[tid] = make_float2(beta[tid] - mean[tid] * sc, w2[tid]);
    }

    const int tile = (int)(__brev((unsigned)blockIdx.x) >> 21);  // 11-bit bitrev, 2048 tiles
    const int px0g = tile * PXT;
    const int b    = px0g >> 17;               // THW = 2^17
    const int px0  = px0g & (THW - 1);

    const float* featsb = feats + (long)b * NF * THW + px0;
    const float* psb    = ps    + (long)b * NP * THW + px0;
    const long   sstr   = (long)NB * NF * THW;

    // wave wv stages f-pairs wv*8..wv*8+7; each lane loads BOTH planes of a
    // pair at its own px 2*lane (float2 = 8B/lane, 512B contiguous per instr).
    auto stage_load = [&](int s, float2* v) {
        const float* base = featsb + (long)s * sstr;
        #pragma unroll
        for (int i = 0; i < 8; ++i) {
            const int fp = wv * 8 + i;
            v[2 * i]     = ((const float2*)(base + (long)(2 * fp)     * THW))[lane];
            v[2 * i + 1] = ((const float2*)(base + (long)(2 * fp + 1) * THW))[lane];
        }
    };
    auto stage_write = [&](const float2* v, int buf) {
        #pragma unroll
        for (int i = 0; i < 8; ++i) {
            const int fp = wv * 8 + i;
            uint2 w;
            w.x = pk2(v[2 * i].x, v[2 * i + 1].x);
            w.y = pk2(v[2 * i].y, v[2 * i + 1].y);
            *((uint2*)&fbuf[buf][fp][2 * lane]) = w;
        }
    };

    // ---- prologue: p (2 pairs/wave) + s0 staged; s1 loads left in flight
    float2 vA[16], vB[16];
    {
        #pragma unroll
        for (int i = 0; i < 2; ++i) {
            const int pp = wv * 2 + i;
            float2 a = ((const float2*)(psb + (long)(2 * pp)     * THW))[lane];
            float2 c = ((const float2*)(psb + (long)(2 * pp + 1) * THW))[lane];
            uint2 w;
            w.x = pk2(a.x, c.x);
            w.y = pk2(a.y, c.y);
            *((uint2*)&pbuf[pp][2 * lane]) = w;
        }
        stage_load(0, vA);
        stage_write(vA, 0);
        stage_load(1, vA);            // s1 in flight across the barrier
    }
    lds_barrier();

    // ---- hoist A fragments (w1*scale); shift/w2 read per-use from tbl
    FragU afr[5];
    {
        const uint32_t abase = (uint32_t)(ln * 44 + hi * 4);
        #pragma unroll
        for (int k = 0; k < 5; ++k)
            afr[k].q = *((const uint4*)&w1lds[abase + k * 8]);
    }

    const int pxloc = wv * 32 + ln;

    // ---- p fragment: direct dword reads (pair hi*4+r = planes {8hi+2r, 8hi+2r+1})
    FragU bp;
    #pragma unroll
    for (int r = 0; r < 4; ++r)
        bp.u[r] = pbuf[hi * 4 + r][pxloc];

    auto consume = [&](int buf, FragU* pk) -> float {
        #pragma unroll
        for (int kb = 0; kb < 4; ++kb)
            #pragma unroll
            for (int r = 0; r < 4; ++r)
                pk[kb].u[r] = fbuf[buf][kb * 8 + hi * 4 + r][pxloc];
        f32x16 acc;
        #pragma unroll
        for (int r = 0; r < 16; ++r) acc[r] = 0.f;
        acc = __builtin_amdgcn_mfma_f32_32x32x16_bf16(afr[4].v, bp.v,    acc, 0, 0, 0);
        acc = __builtin_amdgcn_mfma_f32_32x32x16_bf16(afr[0].v, pk[0].v, acc, 0, 0, 0);
        acc = __builtin_amdgcn_mfma_f32_32x32x16_bf16(afr[1].v, pk[1].v, acc, 0, 0, 0);
        acc = __builtin_amdgcn_mfma_f32_32x32x16_bf16(afr[2].v, pk[2].v, acc, 0, 0, 0);
        acc = __builtin_amdgcn_mfma_f32_32x32x16_bf16(afr[3].v, pk[3].v, acc, 0, 0, 0);
        float pp4[4] = {0.f, 0.f, 0.f, 0.f};
        #pragma unroll
        for (int r = 0; r < 16; ++r) {
            float2 t = tbl[(r & 3) + 8 * (r >> 2) + 4 * hi];
            float h = fmaxf(acc[r] + t.x, 0.f);
            pp4[r & 3] = fmaf(h, t.y, pp4[r & 3]);
        }
        float part = (pp4[0] + pp4[1]) + (pp4[2] + pp4[3]);
        return part + __shfl_xor(part, 32);
    };

    FragU pk0[4], pk1[4], pk2f[4], pk3[4];
    float lg0, lg1, lg2, lg3;

    // ---- phase 0: issue s2; consume s0; commit s1 (vA waited here, ~1.5 phases old)
    stage_load(2, vB);
    asm volatile("" ::: "memory");
    lg0 = consume(0, pk0);
    asm volatile("" ::: "memory");
    stage_write(vA, 1);
    lds_barrier();

    // ---- phase 1: issue s3; consume s1; commit s2 (vB ~2 phases old)
    stage_load(3, vA);
    asm volatile("" ::: "memory");
    lg1 = consume(1, pk1);
    asm volatile("" ::: "memory");
    stage_write(vB, 0);
    lds_barrier();

    // ---- phase 2: consume s2; commit s3
    lg2 = consume(0, pk2f);
    asm volatile("" ::: "memory");
    stage_write(vA, 1);
    lds_barrier();

    // ---- phase 3
    lg3 = consume(1, pk3);

    // ---- softmax over 4 logits (b2 shift-invariant: skipped)
    const float m   = fmaxf(fmaxf(lg0, lg1), fmaxf(lg2, lg3));
    const float e0  = __expf(lg0 - m), e1 = __expf(lg1 - m);
    const float e2  = __expf(lg2 - m), e3 = __expf(lg3 - m);
    const float inv = 1.f / (e0 + e1 + e2 + e3);
    const float a0 = e0 * inv, a1 = e1 * inv, a2 = e2 * inv, a3 = e3 * inv;

    const int thw = px0 + pxloc;

    // ---- out[b][f][thw] = sum_s alpha_s * feats_s (from bf16 frags), f = k*16+hi*8+j
    float* ob = out + ((long)(b * NF + hi * 8)) * THW + thw;
    #pragma unroll
    for (int k = 0; k < 4; ++k)
        #pragma unroll
        for (int r = 0; r < 4; ++r) {
            float vlo = a0 * lo16(pk0[k].u[r]);
            float vhi = a0 * hi16(pk0[k].u[r]);
            vlo = fmaf(a1, lo16(pk1[k].u[r]), vlo);
            vhi = fmaf(a1, hi16(pk1[k].u[r]), vhi);
            vlo = fmaf(a2, lo16(pk2f[k].u[r]), vlo);
            vhi = fmaf(a2, hi16(pk2f[k].u[r]), vhi);
            vlo = fmaf(a3, lo16(pk3[k].u[r]), vlo);
            vhi = fmaf(a3, hi16(pk3[k].u[r]), vhi);
            ob[(long)(k * 16 + 2 * r)     * THW] = vlo;
            ob[(long)(k * 16 + 2 * r + 1) * THW] = vhi;
        }

    // ---- alpha[b][s][thw] at offset B*F*THW; hi=0 -> s=0,1 ; hi=1 -> s=2,3
    float* ab = out + (long)NB * NF * THW + ((long)(b * NS + hi * 2)) * THW + thw;
    ab[0]   = hi ? a2 : a0;
    ab[THW] = hi ? a3 : a1;
}

extern "C" void kernel_launch(void* const* d_in, const int* in_sizes, int n_in,
                              void* d_out, int out_size, void* d_ws, size_t ws_size,
                              hipStream_t stream) {
    const float* feats = (const float*)d_in[0];
    const float* ps    = (const float*)d_in[1];
    const float* w1    = (const float*)d_in[2];
    const float* gamma = (const float*)d_in[3];
    const float* beta  = (const float*)d_in[4];
    const float* mean  = (const float*)d_in[5];
    const float* var   = (const float*)d_in[6];
    const float* w2    = (const float*)d_in[7];
    float* out = (float*)d_out;

    dim3 grid(2048), block(256);   // 2048 blocks x 128 px = 262144 pixels
    hipLaunchKernelGGL(gssm_kernel, grid, block, 0, stream,
                       feats, ps, w1, gamma, beta, mean, var, w2, out);
}